// Round 1
// baseline (7160.109 us; speedup 1.0000x reference)
//
#include <hip/hip_runtime.h>

#define LL 9216            // 96*96
#define TOT 36864          // 4*LL
#define CHK 144
#define NSEG 144           // sort segments of 256 per batch
#define EPS_N 5e-5f

// ---------------- K1: fused 3x3 SAME convs (wm->xe[16], wa->ye[64], wf->fe[64]) ----
__global__ __launch_bounds__(256) void k_conv(
    const float* __restrict__ x,
    const float* __restrict__ wm, const float* __restrict__ bm,
    const float* __restrict__ wa, const float* __restrict__ ba,
    const float* __restrict__ wf, const float* __restrict__ bf,
    float* __restrict__ xe, float* __restrict__ ye, float* __restrict__ fe)
{
    __shared__ float xl[6400];          // [64 ch][10][10] halo tile
    int b = blockIdx.x;
    int n = b / 144, tile = b % 144;
    int ty0 = (tile / 12) * 8, tx0 = (tile % 12) * 8;
    int tid = threadIdx.x;
    for (int li = tid; li < 6400; li += 256) {
        int c = li / 100, s = li % 100;
        int yy = s / 10, xx = s % 10;
        int gy = ty0 + yy - 1, gx = tx0 + xx - 1;
        float v = 0.f;
        if ((unsigned)gy < 96u && (unsigned)gx < 96u)
            v = x[((n * 64 + c) * 96 + gy) * 96 + gx];
        xl[li] = v;
    }
    __syncthreads();
    int pg = tid & 15, og = tid >> 4;         // 16 pos-groups x 16 chan-groups(9 ch)
    int row = pg >> 1, col0 = (pg & 1) * 4;   // 4 horizontal positions per thread
    const float* wb[9]; float bias[9]; float* op[9]; int ostr[9];
    #pragma unroll
    for (int j = 0; j < 9; ++j) {
        int o = og * 9 + j;
        if (o < 16)      { wb[j] = wm + o*576;      bias[j] = bm[o];    op[j] = xe + (size_t)n*LL*16 + o;      ostr[j] = 16; }
        else if (o < 80) { wb[j] = wa + (o-16)*576; bias[j] = ba[o-16]; op[j] = ye + (size_t)n*LL*64 + (o-16); ostr[j] = 64; }
        else             { wb[j] = wf + (o-80)*576; bias[j] = bf[o-80]; op[j] = fe + (size_t)n*LL*64 + (o-80); ostr[j] = 64; }
    }
    float acc[9][4];
    #pragma unroll
    for (int j = 0; j < 9; ++j)
        #pragma unroll
        for (int u = 0; u < 4; ++u) acc[j][u] = 0.f;
    for (int c = 0; c < 64; ++c) {
        #pragma unroll
        for (int dy = 0; dy < 3; ++dy) {
            float xv[6];
            #pragma unroll
            for (int u = 0; u < 6; ++u)
                xv[u] = xl[c*100 + (row+dy)*10 + col0 + u];
            #pragma unroll
            for (int j = 0; j < 9; ++j) {
                const float* wp = wb[j] + c*9 + dy*3;
                float w0 = wp[0], w1 = wp[1], w2 = wp[2];
                #pragma unroll
                for (int u = 0; u < 4; ++u)
                    acc[j][u] += w0*xv[u] + w1*xv[u+1] + w2*xv[u+2];
            }
        }
    }
    int tbase = (ty0 + row) * 96 + tx0 + col0;
    #pragma unroll
    for (int j = 0; j < 9; ++j)
        #pragma unroll
        for (int u = 0; u < 4; ++u) {
            float v = acc[j][u] + bias[j];
            op[j][(size_t)(tbase + u) * ostr[j]] = v > 0.f ? v : 0.f;
        }
}

// ---------------- K2: LSH codes = argmax over 64 rotated dirs per round ----------
__global__ __launch_bounds__(256) void k_codes(
    const float* __restrict__ xe, const float* __restrict__ rot,
    unsigned char* __restrict__ codes)
{
    __shared__ float rotT[4096];   // [h*64+i][16]
    int tid = threadIdx.x;
    for (int e = tid; e < 4096; e += 256) {
        int f = e >> 8, r = e & 255;
        rotT[r * 16 + f] = rot[f * 256 + r];   // rot is (16,4,64)
    }
    __syncthreads();
    int P = blockIdx.x * 64 + (tid & 63);
    int h = tid >> 6;
    int n = P / LL, t = P % LL;
    const float4* xp = (const float4*)(xe + ((size_t)n * LL + t) * 16);
    float4 q0 = xp[0], q1 = xp[1], q2 = xp[2], q3 = xp[3];
    float best = -1e30f; int bi = 0;
    const float* rp = rotT + h * 1024;
    for (int i = 0; i < 64; ++i) {
        const float4* r4 = (const float4*)(rp + i * 16);
        float4 a = r4[0], b = r4[1], c = r4[2], d = r4[3];
        float v = (q0.x*a.x + q0.y*a.y + q0.z*a.z + q0.w*a.w)
                + (q1.x*b.x + q1.y*b.y + q1.z*b.z + q1.w*b.w)
                + (q2.x*c.x + q2.y*c.y + q2.z*c.z + q2.w*c.w)
                + (q3.x*d.x + q3.y*d.y + q3.z*d.z + q3.w*d.w);
        if (v > best) { best = v; bi = i; }   // strict > keeps first max (jnp.argmax)
    }
    codes[(size_t)n * TOT + h * LL + t] = (unsigned char)(h * 64 + bi);
}

// ---------------- K3: stable counting sort (hist -> scan -> place) --------------
__global__ __launch_bounds__(256) void k_hist(
    const unsigned char* __restrict__ codes, int* __restrict__ hist)
{
    __shared__ int lh[256];
    int b = blockIdx.x, n = b / NSEG, seg = b % NSEG;
    int tid = threadIdx.x;
    lh[tid] = 0;
    __syncthreads();
    int code = codes[(size_t)n * TOT + seg * 256 + tid];
    atomicAdd(&lh[code], 1);
    __syncthreads();
    hist[(b << 8) + tid] = lh[tid];
}

__global__ __launch_bounds__(256) void k_scan(int* __restrict__ hist)
{
    __shared__ int tot[256];
    __shared__ int bstart[256];
    int n = blockIdx.x, tid = threadIdx.x;
    int* hp = hist + n * NSEG * 256;
    int running = 0;
    for (int seg = 0; seg < NSEG; ++seg) {
        int v = hp[seg * 256 + tid];
        hp[seg * 256 + tid] = running;
        running += v;
    }
    tot[tid] = running;
    __syncthreads();
    if (tid == 0) {
        int r = 0;
        for (int i = 0; i < 256; ++i) { bstart[i] = r; r += tot[i]; }
    }
    __syncthreads();
    int bs = bstart[tid];
    for (int seg = 0; seg < NSEG; ++seg)
        hp[seg * 256 + tid] += bs;
}

__global__ __launch_bounds__(256) void k_place(
    const unsigned char* __restrict__ codes, const int* __restrict__ hist,
    int* __restrict__ idx)
{
    __shared__ unsigned char cl[256];
    int b = blockIdx.x, n = b / NSEG, seg = b % NSEG;
    int tid = threadIdx.x;
    int my = codes[(size_t)n * TOT + seg * 256 + tid];
    cl[tid] = (unsigned char)my;
    __syncthreads();
    int rank = 0;
    for (int j = 0; j < tid; ++j) rank += (cl[j] == my);
    int pos = hist[(b << 8) + my] + rank;
    idx[(size_t)n * TOT + pos] = seg * 256 + tid;
}

// ---------------- K4: bucketed attention (flash-tiled over 432 keys) -------------
// one block per (n,h,chunk): 512 blocks, 256 threads
__global__ __launch_bounds__(256) void k_attn(
    const float* __restrict__ xe, const float* __restrict__ ye,
    const float* __restrict__ fe, const int* __restrict__ idx,
    const float* __restrict__ fc1_w, const float* __restrict__ fc1_b,
    const float* __restrict__ fc2_w, const float* __restrict__ fc2_b,
    float* __restrict__ ret, float* __restrict__ bsc)
{
    __shared__ float xm_self[144 * 20];   // normalized query rows (stride 20, 16B-aligned)
    __shared__ float xm_col[48 * 20];     // normalized key rows of current tile
    __shared__ int   t_arr[432];
    __shared__ float s_arr[144], m_run[144], l_run[144], alpha_arr[144];
    __shared__ float fa_t[48 * 68];       // f-tile (stride 68, 16B-aligned)
    __shared__ float hid_t[48 * 148];     // hid transposed [jt][m] (stride 148, 16B-aligned)
    __shared__ float raw_t[144 * 48];     // raw scores then exp'd scores
    __shared__ float ya_t[48 * 64];       // y-tile

    int b = blockIdx.x;
    int n = b >> 8, rem = b & 255;
    int h = rem >> 6, k = rem & 63;
    int tid = threadIdx.x;

    // gather t for all 432 adjacency rows ([self, k-1, k+1]); build normalized queries
    for (int r = tid; r < 432; r += 256) {
        int region = r / 144, i = r % 144;
        int dk = (region == 0) ? 0 : (region == 1 ? -1 : 1);
        int ck = (k + dk + 64) & 63;
        int p = h * LL + ck * CHK + i;
        int orig = idx[(size_t)n * TOT + p];
        int t = orig - h * LL;
        t_arr[r] = t;
        if (r < 144) {
            const float4* xp = (const float4*)(xe + ((size_t)n * LL + t) * 16);
            float4 a = xp[0], b2 = xp[1], c2 = xp[2], d2 = xp[3];
            float nn = a.x*a.x + a.y*a.y + a.z*a.z + a.w*a.w
                     + b2.x*b2.x + b2.y*b2.y + b2.z*b2.z + b2.w*b2.w
                     + c2.x*c2.x + c2.y*c2.y + c2.z*c2.z + c2.w*c2.w
                     + d2.x*d2.x + d2.y*d2.y + d2.z*d2.z + d2.w*d2.w;
            float s = sqrtf(nn); s = fmaxf(s, EPS_N);
            float inv = 1.f / s;
            float* dst = xm_self + i * 20;
            dst[0]=a.x*inv;  dst[1]=a.y*inv;  dst[2]=a.z*inv;  dst[3]=a.w*inv;
            dst[4]=b2.x*inv; dst[5]=b2.y*inv; dst[6]=b2.z*inv; dst[7]=b2.w*inv;
            dst[8]=c2.x*inv; dst[9]=c2.y*inv; dst[10]=c2.z*inv; dst[11]=c2.w*inv;
            dst[12]=d2.x*inv; dst[13]=d2.y*inv; dst[14]=d2.z*inv; dst[15]=d2.w*inv;
            s_arr[i] = s; m_run[i] = -1e30f; l_run[i] = 0.f;
        }
    }
    float4 acc4[9];
    #pragma unroll
    for (int q = 0; q < 9; ++q) acc4[q] = make_float4(0.f, 0.f, 0.f, 0.f);
    int si = tid >> 4, tj = tid & 15;   // 16x16 thread grid for matmul steps
    int cg = tid & 15, ir = tid >> 4;   // ret mapping: c = cg*4.., rows i = ir+16q
    __syncthreads();

    for (int T = 0; T < 9; ++T) {
        int r0 = T * 48;
        // ---- stage f/y tiles and normalized key tile ----
        for (int e = tid; e < 48 * 16; e += 256) {
            int jt = e >> 4, c4 = e & 15;
            int t = t_arr[r0 + jt];
            const float4* sf = (const float4*)(fe + ((size_t)n * LL + t) * 64);
            const float4* sy = (const float4*)(ye + ((size_t)n * LL + t) * 64);
            *(float4*)(fa_t + jt * 68 + c4 * 4) = sf[c4];
            *(float4*)(ya_t + jt * 64 + c4 * 4) = sy[c4];
        }
        if (tid < 48) {
            int t = t_arr[r0 + tid];
            const float4* xp = (const float4*)(xe + ((size_t)n * LL + t) * 16);
            float4 a = xp[0], b2 = xp[1], c2 = xp[2], d2 = xp[3];
            float nn = a.x*a.x + a.y*a.y + a.z*a.z + a.w*a.w
                     + b2.x*b2.x + b2.y*b2.y + b2.z*b2.z + b2.w*b2.w
                     + c2.x*c2.x + c2.y*c2.y + c2.z*c2.z + c2.w*c2.w
                     + d2.x*d2.x + d2.y*d2.y + d2.z*d2.z + d2.w*d2.w;
            float s = sqrtf(nn); s = fmaxf(s, EPS_N);
            float inv = 1.f / s;
            float* dst = xm_col + tid * 20;
            dst[0]=a.x*inv;  dst[1]=a.y*inv;  dst[2]=a.z*inv;  dst[3]=a.w*inv;
            dst[4]=b2.x*inv; dst[5]=b2.y*inv; dst[6]=b2.z*inv; dst[7]=b2.w*inv;
            dst[8]=c2.x*inv; dst[9]=c2.y*inv; dst[10]=c2.z*inv; dst[11]=c2.w*inv;
            dst[12]=d2.x*inv; dst[13]=d2.y*inv; dst[14]=d2.z*inv; dst[15]=d2.w*inv;
        }
        __syncthreads();
        // ---- hid = relu(fa @ fc1^T + b1); thread computes 9m x 3jt ----
        {
            float hv[9][3];
            #pragma unroll
            for (int u = 0; u < 9; ++u) { hv[u][0]=0.f; hv[u][1]=0.f; hv[u][2]=0.f; }
            #pragma unroll
            for (int cc = 0; cc < 64; cc += 4) {
                float4 f0 = *(const float4*)(fa_t + (tj*3+0)*68 + cc);
                float4 f1 = *(const float4*)(fa_t + (tj*3+1)*68 + cc);
                float4 f2 = *(const float4*)(fa_t + (tj*3+2)*68 + cc);
                #pragma unroll
                for (int u = 0; u < 9; ++u) {
                    float4 w4 = *(const float4*)(fc1_w + (si*9+u)*64 + cc);
                    hv[u][0] += w4.x*f0.x + w4.y*f0.y + w4.z*f0.z + w4.w*f0.w;
                    hv[u][1] += w4.x*f1.x + w4.y*f1.y + w4.z*f1.z + w4.w*f1.w;
                    hv[u][2] += w4.x*f2.x + w4.y*f2.y + w4.z*f2.z + w4.w*f2.w;
                }
            }
            #pragma unroll
            for (int u = 0; u < 9; ++u) {
                int m = si*9+u;
                float bb = fc1_b[m];
                #pragma unroll
                for (int v = 0; v < 3; ++v) {
                    float val = hv[u][v] + bb;
                    hid_t[(tj*3+v)*148 + m] = val > 0.f ? val : 0.f;
                }
            }
        }
        __syncthreads();
        // ---- raw = s_i * (q_i . k_j) + fc2 + b2 ; thread computes 9i x 3jt ----
        {
            float rv[9][3];
            #pragma unroll
            for (int u = 0; u < 9; ++u) {
                int i = si*9 + u;
                const float4* xi4 = (const float4*)(xm_self + i * 20);
                float4 x0 = xi4[0], x1 = xi4[1], x2 = xi4[2], x3 = xi4[3];
                float ss = s_arr[i], bb = fc2_b[i];
                #pragma unroll
                for (int v = 0; v < 3; ++v) {
                    const float4* xj4 = (const float4*)(xm_col + (tj*3+v) * 20);
                    float4 y0 = xj4[0], y1 = xj4[1], y2 = xj4[2], y3 = xj4[3];
                    float d = (x0.x*y0.x + x0.y*y0.y + x0.z*y0.z + x0.w*y0.w)
                            + (x1.x*y1.x + x1.y*y1.y + x1.z*y1.z + x1.w*y1.w)
                            + (x2.x*y2.x + x2.y*y2.y + x2.z*y2.z + x2.w*y2.w)
                            + (x3.x*y3.x + x3.y*y3.y + x3.z*y3.z + x3.w*y3.w);
                    rv[u][v] = ss * d + bb;
                }
            }
            #pragma unroll
            for (int mm = 0; mm < 144; mm += 4) {
                float4 h0 = *(const float4*)(hid_t + (tj*3+0)*148 + mm);
                float4 h1 = *(const float4*)(hid_t + (tj*3+1)*148 + mm);
                float4 h2 = *(const float4*)(hid_t + (tj*3+2)*148 + mm);
                #pragma unroll
                for (int u = 0; u < 9; ++u) {
                    float4 w4 = *(const float4*)(fc2_w + (si*9+u)*144 + mm);
                    rv[u][0] += w4.x*h0.x + w4.y*h0.y + w4.z*h0.z + w4.w*h0.w;
                    rv[u][1] += w4.x*h1.x + w4.y*h1.y + w4.z*h1.z + w4.w*h1.w;
                    rv[u][2] += w4.x*h2.x + w4.y*h2.y + w4.z*h2.z + w4.w*h2.w;
                }
            }
            #pragma unroll
            for (int u = 0; u < 9; ++u)
                #pragma unroll
                for (int v = 0; v < 3; ++v)
                    raw_t[(si*9+u)*48 + tj*3+v] = rv[u][v];
        }
        __syncthreads();
        // ---- online softmax over this tile (row-parallel) ----
        if (tid < 144) {
            float mt = -1e30f;
            for (int jt = 0; jt < 48; ++jt) mt = fmaxf(mt, raw_t[tid*48 + jt]);
            float mo = m_run[tid];
            float mn = fmaxf(mo, mt);
            float a = expf(mo - mn);
            float ssum = 0.f;
            for (int jt = 0; jt < 48; ++jt) {
                float e2 = expf(raw_t[tid*48 + jt] - mn);
                raw_t[tid*48 + jt] = e2;
                ssum += e2;
            }
            l_run[tid] = l_run[tid] * a + ssum;
            m_run[tid] = mn;
            alpha_arr[tid] = a;
        }
        __syncthreads();
        // ---- ret accumulate: acc[i][c] = acc*alpha + score @ ya ----
        {
            #pragma unroll
            for (int q = 0; q < 9; ++q) {
                float a = alpha_arr[ir + 16*q];
                acc4[q].x *= a; acc4[q].y *= a; acc4[q].z *= a; acc4[q].w *= a;
            }
            const float4* ya4 = (const float4*)ya_t;
            for (int jt = 0; jt < 48; ++jt) {
                float4 yv = ya4[jt*16 + cg];
                #pragma unroll
                for (int q = 0; q < 9; ++q) {
                    float sv = raw_t[(ir + 16*q)*48 + jt];
                    acc4[q].x += sv*yv.x; acc4[q].y += sv*yv.y;
                    acc4[q].z += sv*yv.z; acc4[q].w += sv*yv.w;
                }
            }
        }
        __syncthreads();
    }
    // ---- epilogue: scatter to unsorted (n,h,t) so no undo pass is needed ----
    if (tid < 144) {
        bsc[((size_t)n*4 + h)*LL + t_arr[tid]] = m_run[tid] + logf(l_run[tid]);
    }
    #pragma unroll
    for (int q = 0; q < 9; ++q) {
        int i = ir + 16*q;
        float inv = 1.f / l_run[i];
        int t = t_arr[i];
        float4 v = acc4[q];
        v.x *= inv; v.y *= inv; v.z *= inv; v.w *= inv;
        *(float4*)(ret + (((size_t)n*4 + h)*LL + t)*64 + cg*4) = v;
    }
}

// ---------------- K5: softmax over rounds + residual, NCHW output ----------------
__global__ __launch_bounds__(256) void k_final(
    const float* __restrict__ ret, const float* __restrict__ bsc,
    const float* __restrict__ x, float* __restrict__ out)
{
    __shared__ float pr[4][64];
    __shared__ float accl[64 * 65];
    int b = blockIdx.x, n = b / 144;
    int t0 = (b % 144) * 64;
    int tid = threadIdx.x;
    if (tid < 64) {
        int t = t0 + tid;
        float b0 = bsc[((size_t)n*4 + 0)*LL + t];
        float b1 = bsc[((size_t)n*4 + 1)*LL + t];
        float b2 = bsc[((size_t)n*4 + 2)*LL + t];
        float b3 = bsc[((size_t)n*4 + 3)*LL + t];
        float mx = fmaxf(fmaxf(b0, b1), fmaxf(b2, b3));
        float e0 = expf(b0-mx), e1 = expf(b1-mx), e2 = expf(b2-mx), e3 = expf(b3-mx);
        float inv = 1.f / (e0 + e1 + e2 + e3);
        pr[0][tid] = e0*inv; pr[1][tid] = e1*inv; pr[2][tid] = e2*inv; pr[3][tid] = e3*inv;
    }
    __syncthreads();
    int cc = tid & 63, tt4 = tid >> 6;
    #pragma unroll
    for (int q = 0; q < 16; ++q) {
        int tt = tt4 + 4*q;
        int t = t0 + tt;
        float v = 0.f;
        #pragma unroll
        for (int h2 = 0; h2 < 4; ++h2)
            v += ret[(((size_t)n*4 + h2)*LL + t)*64 + cc] * pr[h2][tt];
        accl[cc*65 + tt] = v;
    }
    __syncthreads();
    int tt = tid & 63, c4 = tid >> 6;
    #pragma unroll
    for (int q = 0; q < 16; ++q) {
        int ch = c4 + 4*q;
        size_t o = ((size_t)n*64 + ch)*LL + t0 + tt;
        out[o] = accl[ch*65 + tt] + x[o];   // RES_SCALE = 1.0
    }
}

// ---------------- launcher ----------------
extern "C" void kernel_launch(void* const* d_in, const int* in_sizes, int n_in,
                              void* d_out, int out_size, void* d_ws, size_t ws_size,
                              hipStream_t stream)
{
    const float* x    = (const float*)d_in[0];
    const float* rot  = (const float*)d_in[1];
    const float* wm   = (const float*)d_in[2];
    const float* bm   = (const float*)d_in[3];
    const float* wa   = (const float*)d_in[4];
    const float* ba   = (const float*)d_in[5];
    const float* wf   = (const float*)d_in[6];
    const float* bf   = (const float*)d_in[7];
    const float* fc1w = (const float*)d_in[8];
    const float* fc1b = (const float*)d_in[9];
    const float* fc2w = (const float*)d_in[10];
    const float* fc2b = (const float*)d_in[11];
    float* out = (float*)d_out;

    char* ws = (char*)d_ws;
    float* xe            = (float*)(ws + 0);          // 2*9216*16 f32
    float* ye            = (float*)(ws + 1179648);    // 2*9216*64 f32
    float* fe            = (float*)(ws + 5898240);    // 2*9216*64 f32
    unsigned char* codes = (unsigned char*)(ws + 10616832);  // 2*36864 u8
    int* hist            = (int*)(ws + 10690560);     // 2*144*256 i32
    int* idxb            = (int*)(ws + 10985472);     // 2*36864 i32
    float* retb          = (float*)(ws + 11575296);   // 2*4*9216*64 f32
    float* bscb          = (float*)(ws + 30449664);   // 2*36864 f32  (end: 31039488)

    k_conv <<<288, 256, 0, stream>>>(x, wm, bm, wa, ba, wf, bf, xe, ye, fe);
    k_codes<<<288, 256, 0, stream>>>(xe, rot, codes);
    k_hist <<<288, 256, 0, stream>>>(codes, hist);
    k_scan <<<2,   256, 0, stream>>>(hist);
    k_place<<<288, 256, 0, stream>>>(codes, hist, idxb);
    k_attn <<<512, 256, 0, stream>>>(xe, ye, fe, idxb, fc1w, fc1b, fc2w, fc2b, retb, bscb);
    k_final<<<288, 256, 0, stream>>>(retb, bscb, x, out);
}

// Round 2
// 525.596 us; speedup vs baseline: 13.6228x; 13.6228x over previous
//
#include <hip/hip_runtime.h>

#define LL 9216            // 96*96
#define TOT 36864          // 4*LL
#define CHK 144
#define NSEG 144
#define EPS_N 5e-5f

__device__ __forceinline__ float dot4(float4 a, float4 b) {
    return a.x*b.x + a.y*b.y + a.z*b.z + a.w*b.w;
}

// ---------------- K1: fused 3x3 SAME convs (wm->xe[16], wa->ye[64], wf->fe[64]) ----
__global__ __launch_bounds__(256) void k_conv(
    const float* __restrict__ x,
    const float* __restrict__ wm, const float* __restrict__ bm,
    const float* __restrict__ wa, const float* __restrict__ ba,
    const float* __restrict__ wf, const float* __restrict__ bf,
    float* __restrict__ xe, float* __restrict__ ye, float* __restrict__ fe)
{
    __shared__ float xl[6400];          // [64 ch][10][10] halo tile
    int b = blockIdx.x;
    int n = b / 144, tile = b % 144;
    int ty0 = (tile / 12) * 8, tx0 = (tile % 12) * 8;
    int tid = threadIdx.x;
    for (int li = tid; li < 6400; li += 256) {
        int c = li / 100, s = li % 100;
        int yy = s / 10, xx = s % 10;
        int gy = ty0 + yy - 1, gx = tx0 + xx - 1;
        float v = 0.f;
        if ((unsigned)gy < 96u && (unsigned)gx < 96u)
            v = x[((n * 64 + c) * 96 + gy) * 96 + gx];
        xl[li] = v;
    }
    __syncthreads();
    int pg = tid & 15, og = tid >> 4;
    int row = pg >> 1, col0 = (pg & 1) * 4;
    const float* wb[9]; float bias[9]; float* op[9]; int ostr[9];
    #pragma unroll
    for (int j = 0; j < 9; ++j) {
        int o = og * 9 + j;
        if (o < 16)      { wb[j] = wm + o*576;      bias[j] = bm[o];    op[j] = xe + (size_t)n*LL*16 + o;      ostr[j] = 16; }
        else if (o < 80) { wb[j] = wa + (o-16)*576; bias[j] = ba[o-16]; op[j] = ye + (size_t)n*LL*64 + (o-16); ostr[j] = 64; }
        else             { wb[j] = wf + (o-80)*576; bias[j] = bf[o-80]; op[j] = fe + (size_t)n*LL*64 + (o-80); ostr[j] = 64; }
    }
    float acc[9][4];
    #pragma unroll
    for (int j = 0; j < 9; ++j)
        #pragma unroll
        for (int u = 0; u < 4; ++u) acc[j][u] = 0.f;
    for (int c = 0; c < 64; ++c) {
        #pragma unroll
        for (int dy = 0; dy < 3; ++dy) {
            float xv[6];
            #pragma unroll
            for (int u = 0; u < 6; ++u)
                xv[u] = xl[c*100 + (row+dy)*10 + col0 + u];
            #pragma unroll
            for (int j = 0; j < 9; ++j) {
                const float* wp = wb[j] + c*9 + dy*3;
                float w0 = wp[0], w1 = wp[1], w2 = wp[2];
                #pragma unroll
                for (int u = 0; u < 4; ++u)
                    acc[j][u] += w0*xv[u] + w1*xv[u+1] + w2*xv[u+2];
            }
        }
    }
    int tbase = (ty0 + row) * 96 + tx0 + col0;
    #pragma unroll
    for (int j = 0; j < 9; ++j)
        #pragma unroll
        for (int u = 0; u < 4; ++u) {
            float v = acc[j][u] + bias[j];
            op[j][(size_t)(tbase + u) * ostr[j]] = v > 0.f ? v : 0.f;
        }
}

// ---------------- K2: LSH codes + normalized queries xn ----------------
__global__ __launch_bounds__(256) void k_codes(
    const float* __restrict__ xe, const float* __restrict__ rot,
    unsigned char* __restrict__ codes, float* __restrict__ xn)
{
    __shared__ float rotT[4096];   // [h*64+i][16]
    int tid = threadIdx.x;
    for (int e = tid; e < 4096; e += 256) {
        int f = e >> 8, r = e & 255;
        rotT[r * 16 + f] = rot[f * 256 + r];   // rot is (16,4,64)
    }
    __syncthreads();
    int P = blockIdx.x * 64 + (tid & 63);
    int h = tid >> 6;
    int n = P / LL, t = P % LL;
    const float4* xp = (const float4*)(xe + ((size_t)n * LL + t) * 16);
    float4 q0 = xp[0], q1 = xp[1], q2 = xp[2], q3 = xp[3];
    if (h == 0) {
        float nn = dot4(q0,q0) + dot4(q1,q1) + dot4(q2,q2) + dot4(q3,q3);
        float s = fmaxf(sqrtf(nn), EPS_N);
        float inv = 1.f / s;
        float4* dst = (float4*)(xn + ((size_t)n * LL + t) * 16);
        dst[0] = make_float4(q0.x*inv, q0.y*inv, q0.z*inv, q0.w*inv);
        dst[1] = make_float4(q1.x*inv, q1.y*inv, q1.z*inv, q1.w*inv);
        dst[2] = make_float4(q2.x*inv, q2.y*inv, q2.z*inv, q2.w*inv);
        dst[3] = make_float4(q3.x*inv, q3.y*inv, q3.z*inv, q3.w*inv);
    }
    float best = -1e30f; int bi = 0;
    const float* rp = rotT + h * 1024;
    for (int i = 0; i < 64; ++i) {
        const float4* r4 = (const float4*)(rp + i * 16);
        float v = dot4(q0, r4[0]) + dot4(q1, r4[1]) + dot4(q2, r4[2]) + dot4(q3, r4[3]);
        if (v > best) { best = v; bi = i; }   // strict > = first max (jnp.argmax)
    }
    codes[(size_t)n * TOT + h * LL + t] = (unsigned char)(h * 64 + bi);
}

// ---------------- K3: stable counting sort (hist -> scan -> place) --------------
__global__ __launch_bounds__(256) void k_hist(
    const unsigned char* __restrict__ codes, int* __restrict__ hist)
{
    __shared__ int lh[256];
    int b = blockIdx.x, n = b / NSEG, seg = b % NSEG;
    int tid = threadIdx.x;
    lh[tid] = 0;
    __syncthreads();
    int code = codes[(size_t)n * TOT + seg * 256 + tid];
    atomicAdd(&lh[code], 1);
    __syncthreads();
    hist[(b << 8) + tid] = lh[tid];
}

__global__ __launch_bounds__(256) void k_scan(int* __restrict__ hist)
{
    __shared__ int tot[256];
    __shared__ int bstart[256];
    int n = blockIdx.x, tid = threadIdx.x;
    int* hp = hist + n * NSEG * 256;
    int running = 0;
    for (int seg = 0; seg < NSEG; ++seg) {
        int v = hp[seg * 256 + tid];
        hp[seg * 256 + tid] = running;
        running += v;
    }
    tot[tid] = running;
    __syncthreads();
    if (tid == 0) {
        int r = 0;
        for (int i = 0; i < 256; ++i) { bstart[i] = r; r += tot[i]; }
    }
    __syncthreads();
    int bs = bstart[tid];
    for (int seg = 0; seg < NSEG; ++seg)
        hp[seg * 256 + tid] += bs;
}

__global__ __launch_bounds__(256) void k_place(
    const unsigned char* __restrict__ codes, const int* __restrict__ hist,
    int* __restrict__ idx)
{
    __shared__ unsigned char cl[256];
    int b = blockIdx.x, n = b / NSEG, seg = b % NSEG;
    int tid = threadIdx.x;
    int my = codes[(size_t)n * TOT + seg * 256 + tid];
    cl[tid] = (unsigned char)my;
    __syncthreads();
    int rank = 0;
    for (int j = 0; j < tid; ++j) rank += (cl[j] == my);
    int pos = hist[(b << 8) + my] + rank;
    idx[(size_t)n * TOT + pos] = seg * 256 + tid;
}

// ---------------- K4: fused fc1->relu->fc2 per ROW (row-wise => precomputable) ----
// re2[R, i] = sum_m relu(fe[R,:]@fc1_w[m,:] + b1[m]) * fc2_w[i,m] + b2[i]
// 576 blocks x 32 rows; fc1_w + fc2_w staged in LDS once per block.
__global__ __launch_bounds__(256) void k_fc(
    const float* __restrict__ fe,
    const float* __restrict__ fc1_w, const float* __restrict__ fc1_b,
    const float* __restrict__ fc2_w, const float* __restrict__ fc2_b,
    float* __restrict__ re2)
{
    __shared__ float w1[144 * 64];    // 36864 B
    __shared__ float w2[144 * 144];   // 82944 B
    __shared__ float fet[32 * 68];    // 8704 B (pad 64->68: b128 conflict-free)
    __shared__ float het[32 * 148];   // 18944 B (pad 144->148: b128 conflict-free)
    int tid = threadIdx.x;
    size_t R0 = (size_t)blockIdx.x * 32;
    for (int e4 = tid; e4 < 2304; e4 += 256)
        *(float4*)(w1 + e4 * 4) = *(const float4*)(fc1_w + e4 * 4);
    for (int e4 = tid; e4 < 5184; e4 += 256)
        *(float4*)(w2 + e4 * 4) = *(const float4*)(fc2_w + e4 * 4);
    for (int e4 = tid; e4 < 512; e4 += 256) {
        int r = e4 >> 4, c4 = e4 & 15;
        *(float4*)(fet + r * 68 + c4 * 4) = *(const float4*)(fe + (R0 + r) * 64 + c4 * 4);
    }
    __syncthreads();
    int row = tid & 31, g = tid >> 5;   // 32 rows x 8 output-groups
    float4 fr[16];
    #pragma unroll
    for (int k4 = 0; k4 < 16; ++k4)
        fr[k4] = *(const float4*)(fet + row * 68 + k4 * 4);
    #pragma unroll
    for (int mi = 0; mi < 18; ++mi) {
        int m = g * 18 + mi;
        float acc = 0.f;
        #pragma unroll
        for (int k4 = 0; k4 < 16; ++k4)
            acc += dot4(fr[k4], *(const float4*)(w1 + m * 64 + k4 * 4));
        acc += fc1_b[m];
        het[row * 148 + m] = acc > 0.f ? acc : 0.f;
    }
    __syncthreads();
    #pragma unroll
    for (int ii = 0; ii < 18; ++ii) {
        int i = g * 18 + ii;
        float acc = 0.f;
        #pragma unroll
        for (int k4 = 0; k4 < 36; ++k4)
            acc += dot4(*(const float4*)(het + row * 148 + k4 * 4),
                        *(const float4*)(w2 + i * 144 + k4 * 4));
        re2[(R0 + row) * 144 + i] = acc + fc2_b[i];
    }
}

// ---------------- K5: bucketed attention (gather + QK^T + softmax + PV) ----------
// one block per (n,h,chunk): 512 blocks, 256 threads, 55.7 KB LDS -> 2 blocks/CU
__global__ __launch_bounds__(256) void k_attn(
    const float* __restrict__ xe, const float* __restrict__ xn,
    const float* __restrict__ ye, const float* __restrict__ re2,
    const int* __restrict__ idx,
    float* __restrict__ ret, float* __restrict__ bsc)
{
    __shared__ float xs_s[144 * 16];    // unnormalized query rows
    __shared__ int   t_arr[432];
    __shared__ float m_run[144], l_run[144], alpha_arr[144];
    __shared__ float raw_t[144 * 48];   // scores for current tile
    __shared__ float xnc[48 * 16];      // normalized key tile
    __shared__ float ya_t[48 * 64];     // value tile

    int b = blockIdx.x;
    int n = b >> 8, rem = b & 255;
    int h = rem >> 6, k = rem & 63;
    int tid = threadIdx.x;

    for (int r = tid; r < 432; r += 256) {
        int region = r / 144, i = r - region * 144;
        int dk = (region == 0) ? 0 : (region == 1 ? -1 : 1);
        int ck = (k + dk + 64) & 63;
        t_arr[r] = idx[(size_t)n * TOT + h * LL + ck * CHK + i] - h * LL;
    }
    if (tid < 144) { m_run[tid] = -1e30f; l_run[tid] = 0.f; }
    __syncthreads();
    for (int e4 = tid; e4 < 576; e4 += 256) {
        int r = e4 >> 2, q = e4 & 3;
        *(float4*)(xs_s + r * 16 + q * 4) =
            *(const float4*)(xe + ((size_t)n * LL + t_arr[r]) * 16 + q * 4);
    }
    float4 acc4[9];
    #pragma unroll
    for (int q = 0; q < 9; ++q) acc4[q] = make_float4(0.f, 0.f, 0.f, 0.f);
    int si = tid >> 4, tj = tid & 15;   // qk 16x16 grid
    int cg = tid & 15, ir = tid >> 4;   // pv: c = cg*4.., rows i = ir+16q
    __syncthreads();

    for (int T = 0; T < 9; ++T) {
        int r0 = T * 48;
        // stage raw_t[i][j] = re2[t_j][i] (transposed gather), xnc, ya
        for (int e = tid; e < 6912; e += 256) {
            int j = e / 144, i = e - j * 144;
            raw_t[i * 48 + j] = re2[((size_t)n * LL + t_arr[r0 + j]) * 144 + i];
        }
        for (int e4 = tid; e4 < 192; e4 += 256) {
            int j = e4 >> 2, q = e4 & 3;
            *(float4*)(xnc + j * 16 + q * 4) =
                *(const float4*)(xn + ((size_t)n * LL + t_arr[r0 + j]) * 16 + q * 4);
        }
        for (int e4 = tid; e4 < 768; e4 += 256) {
            int j = e4 >> 4, c4 = e4 & 15;
            *(float4*)(ya_t + j * 64 + c4 * 4) =
                *(const float4*)(ye + ((size_t)n * LL + t_arr[r0 + j]) * 64 + c4 * 4);
        }
        __syncthreads();
        // qk: raw[i][j] += xs_i . xn_j   (thread: 9 i x 3 j)
        {
            float4 xnr[3][4];
            #pragma unroll
            for (int v = 0; v < 3; ++v)
                #pragma unroll
                for (int q = 0; q < 4; ++q)
                    xnr[v][q] = *(const float4*)(xnc + (tj * 3 + v) * 16 + q * 4);
            #pragma unroll
            for (int u = 0; u < 9; ++u) {
                int i = si * 9 + u;
                const float4* xr = (const float4*)(xs_s + i * 16);
                float4 x0 = xr[0], x1 = xr[1], x2 = xr[2], x3 = xr[3];
                #pragma unroll
                for (int v = 0; v < 3; ++v) {
                    float d = dot4(x0, xnr[v][0]) + dot4(x1, xnr[v][1])
                            + dot4(x2, xnr[v][2]) + dot4(x3, xnr[v][3]);
                    raw_t[i * 48 + tj * 3 + v] += d;
                }
            }
        }
        __syncthreads();
        // online softmax per row
        if (tid < 144) {
            float4* rp = (float4*)(raw_t + tid * 48);
            float4 rv[12];
            float mt = -1e30f;
            #pragma unroll
            for (int q = 0; q < 12; ++q) {
                rv[q] = rp[q];
                mt = fmaxf(mt, fmaxf(fmaxf(rv[q].x, rv[q].y), fmaxf(rv[q].z, rv[q].w)));
            }
            float mo = m_run[tid];
            float mn = fmaxf(mo, mt);
            float a = __expf(mo - mn);
            float ssum = 0.f;
            #pragma unroll
            for (int q = 0; q < 12; ++q) {
                rv[q].x = __expf(rv[q].x - mn); rv[q].y = __expf(rv[q].y - mn);
                rv[q].z = __expf(rv[q].z - mn); rv[q].w = __expf(rv[q].w - mn);
                ssum += rv[q].x + rv[q].y + rv[q].z + rv[q].w;
                rp[q] = rv[q];
            }
            l_run[tid] = l_run[tid] * a + ssum;
            m_run[tid] = mn;
            alpha_arr[tid] = a;
        }
        __syncthreads();
        // pv: acc = acc*alpha + score @ ya
        {
            #pragma unroll
            for (int q = 0; q < 9; ++q) {
                float a = alpha_arr[ir + 16 * q];
                acc4[q].x *= a; acc4[q].y *= a; acc4[q].z *= a; acc4[q].w *= a;
            }
            for (int jt4 = 0; jt4 < 12; ++jt4) {
                float4 y0 = *(const float4*)(ya_t + (jt4 * 4 + 0) * 64 + cg * 4);
                float4 y1 = *(const float4*)(ya_t + (jt4 * 4 + 1) * 64 + cg * 4);
                float4 y2 = *(const float4*)(ya_t + (jt4 * 4 + 2) * 64 + cg * 4);
                float4 y3 = *(const float4*)(ya_t + (jt4 * 4 + 3) * 64 + cg * 4);
                #pragma unroll
                for (int q = 0; q < 9; ++q) {
                    float4 sv = *(const float4*)(raw_t + (ir + 16 * q) * 48 + jt4 * 4);
                    acc4[q].x += sv.x*y0.x + sv.y*y1.x + sv.z*y2.x + sv.w*y3.x;
                    acc4[q].y += sv.x*y0.y + sv.y*y1.y + sv.z*y2.y + sv.w*y3.y;
                    acc4[q].z += sv.x*y0.z + sv.y*y1.z + sv.z*y2.z + sv.w*y3.z;
                    acc4[q].w += sv.x*y0.w + sv.y*y1.w + sv.z*y2.w + sv.w*y3.w;
                }
            }
        }
        __syncthreads();
    }
    // epilogue: scatter to unsorted (n,h,t) so no undo pass is needed
    if (tid < 144) {
        bsc[((size_t)n * 4 + h) * LL + t_arr[tid]] = m_run[tid] + __logf(l_run[tid]);
    }
    #pragma unroll
    for (int q = 0; q < 9; ++q) {
        int i = ir + 16 * q;
        float inv = 1.f / l_run[i];
        int t = t_arr[i];
        float4 v = acc4[q];
        v.x *= inv; v.y *= inv; v.z *= inv; v.w *= inv;
        *(float4*)(ret + (((size_t)n * 4 + h) * LL + t) * 64 + cg * 4) = v;
    }
}

// ---------------- K6: softmax over rounds + residual, NCHW output ----------------
__global__ __launch_bounds__(256) void k_final(
    const float* __restrict__ ret, const float* __restrict__ bsc,
    const float* __restrict__ x, float* __restrict__ out)
{
    __shared__ float pr[4][64];
    __shared__ float accl[64 * 65];
    int b = blockIdx.x, n = b / 144;
    int t0 = (b % 144) * 64;
    int tid = threadIdx.x;
    if (tid < 64) {
        int t = t0 + tid;
        float b0 = bsc[((size_t)n*4 + 0)*LL + t];
        float b1 = bsc[((size_t)n*4 + 1)*LL + t];
        float b2 = bsc[((size_t)n*4 + 2)*LL + t];
        float b3 = bsc[((size_t)n*4 + 3)*LL + t];
        float mx = fmaxf(fmaxf(b0, b1), fmaxf(b2, b3));
        float e0 = __expf(b0-mx), e1 = __expf(b1-mx), e2 = __expf(b2-mx), e3 = __expf(b3-mx);
        float inv = 1.f / (e0 + e1 + e2 + e3);
        pr[0][tid] = e0*inv; pr[1][tid] = e1*inv; pr[2][tid] = e2*inv; pr[3][tid] = e3*inv;
    }
    __syncthreads();
    int cc = tid & 63, tt4 = tid >> 6;
    #pragma unroll
    for (int q = 0; q < 16; ++q) {
        int tt = tt4 + 4*q;
        int t = t0 + tt;
        float v = 0.f;
        #pragma unroll
        for (int h2 = 0; h2 < 4; ++h2)
            v += ret[(((size_t)n*4 + h2)*LL + t)*64 + cc] * pr[h2][tt];
        accl[cc*65 + tt] = v;
    }
    __syncthreads();
    int tt = tid & 63, c4 = tid >> 6;
    #pragma unroll
    for (int q = 0; q < 16; ++q) {
        int ch = c4 + 4*q;
        size_t o = ((size_t)n*64 + ch)*LL + t0 + tt;
        out[o] = accl[ch*65 + tt] + x[o];   // RES_SCALE = 1.0
    }
}

// ---------------- launcher ----------------
extern "C" void kernel_launch(void* const* d_in, const int* in_sizes, int n_in,
                              void* d_out, int out_size, void* d_ws, size_t ws_size,
                              hipStream_t stream)
{
    const float* x    = (const float*)d_in[0];
    const float* rot  = (const float*)d_in[1];
    const float* wm   = (const float*)d_in[2];
    const float* bm   = (const float*)d_in[3];
    const float* wa   = (const float*)d_in[4];
    const float* ba   = (const float*)d_in[5];
    const float* wf   = (const float*)d_in[6];
    const float* bf   = (const float*)d_in[7];
    const float* fc1w = (const float*)d_in[8];
    const float* fc1b = (const float*)d_in[9];
    const float* fc2w = (const float*)d_in[10];
    const float* fc2b = (const float*)d_in[11];
    float* out = (float*)d_out;

    char* ws = (char*)d_ws;
    float* xe            = (float*)(ws + 0);          // 2*9216*16  f32 = 1,179,648 B
    float* ye            = (float*)(ws + 1179648);    // 2*9216*64  f32 = 4,718,592 B
    float* fe            = (float*)(ws + 5898240);    // 2*9216*64  f32 = 4,718,592 B
    float* xn            = (float*)(ws + 10616832);   // 2*9216*16  f32 = 1,179,648 B
    float* re2           = (float*)(ws + 11796480);   // 2*9216*144 f32 = 10,616,832 B
    unsigned char* codes = (unsigned char*)(ws + 22413312);  // 2*36864 u8
    int* hist            = (int*)(ws + 22487040);     // 2*144*256 i32
    int* idxb            = (int*)(ws + 22781952);     // 2*36864 i32
    float* retb          = (float*)(ws + 23076864);   // 2*4*9216*64 f32 = 18,874,368 B
    float* bscb          = (float*)(ws + 41951232);   // 2*36864 f32 (end: 42,246,144)

    k_conv <<<288, 256, 0, stream>>>(x, wm, bm, wa, ba, wf, bf, xe, ye, fe);
    k_codes<<<288, 256, 0, stream>>>(xe, rot, codes, xn);
    k_hist <<<288, 256, 0, stream>>>(codes, hist);
    k_scan <<<2,   256, 0, stream>>>(hist);
    k_place<<<288, 256, 0, stream>>>(codes, hist, idxb);
    k_fc   <<<576, 256, 0, stream>>>(fe, fc1w, fc1b, fc2w, fc2b, re2);
    k_attn <<<512, 256, 0, stream>>>(xe, xn, ye, re2, idxb, retb, bscb);
    k_final<<<288, 256, 0, stream>>>(retb, bscb, x, out);
}

// Round 3
// 414.103 us; speedup vs baseline: 17.2907x; 1.2692x over previous
//
#include <hip/hip_runtime.h>
#include <hip/hip_bf16.h>

#define LL 9216            // 96*96
#define TOT 36864          // 4*LL
#define CHK 144
#define NSEG 144
#define EPS_N 5e-5f

typedef __bf16 bf16x8 __attribute__((ext_vector_type(8)));
typedef float f32x4 __attribute__((ext_vector_type(4)));

__device__ __forceinline__ float dot4(float4 a, float4 b) {
    return a.x*b.x + a.y*b.y + a.z*b.z + a.w*b.w;
}
__device__ __forceinline__ unsigned short f2bf(float f) {
    __hip_bfloat16 h = __float2bfloat16(f);
    return *reinterpret_cast<unsigned short*>(&h);
}

// ---------------- K1: fused 3x3 SAME convs (wm->xe[16], wa->ye[64], wf->fe[64]) ----
__global__ __launch_bounds__(256) void k_conv(
    const float* __restrict__ x,
    const float* __restrict__ wm, const float* __restrict__ bm,
    const float* __restrict__ wa, const float* __restrict__ ba,
    const float* __restrict__ wf, const float* __restrict__ bf,
    float* __restrict__ xe, float* __restrict__ ye, float* __restrict__ fe)
{
    __shared__ float xl[6400];          // [64 ch][10][10] halo tile
    int b = blockIdx.x;
    int n = b / 144, tile = b % 144;
    int ty0 = (tile / 12) * 8, tx0 = (tile % 12) * 8;
    int tid = threadIdx.x;
    for (int li = tid; li < 6400; li += 256) {
        int c = li / 100, s = li % 100;
        int yy = s / 10, xx = s % 10;
        int gy = ty0 + yy - 1, gx = tx0 + xx - 1;
        float v = 0.f;
        if ((unsigned)gy < 96u && (unsigned)gx < 96u)
            v = x[((n * 64 + c) * 96 + gy) * 96 + gx];
        xl[li] = v;
    }
    __syncthreads();
    int pg = tid & 15, og = tid >> 4;
    int row = pg >> 1, col0 = (pg & 1) * 4;
    const float* wb[9]; float bias[9]; float* op[9]; int ostr[9];
    #pragma unroll
    for (int j = 0; j < 9; ++j) {
        int o = og * 9 + j;
        if (o < 16)      { wb[j] = wm + o*576;      bias[j] = bm[o];    op[j] = xe + (size_t)n*LL*16 + o;      ostr[j] = 16; }
        else if (o < 80) { wb[j] = wa + (o-16)*576; bias[j] = ba[o-16]; op[j] = ye + (size_t)n*LL*64 + (o-16); ostr[j] = 64; }
        else             { wb[j] = wf + (o-80)*576; bias[j] = bf[o-80]; op[j] = fe + (size_t)n*LL*64 + (o-80); ostr[j] = 64; }
    }
    float acc[9][4];
    #pragma unroll
    for (int j = 0; j < 9; ++j)
        #pragma unroll
        for (int u = 0; u < 4; ++u) acc[j][u] = 0.f;
    for (int c = 0; c < 64; ++c) {
        #pragma unroll
        for (int dy = 0; dy < 3; ++dy) {
            float xv[6];
            #pragma unroll
            for (int u = 0; u < 6; ++u)
                xv[u] = xl[c*100 + (row+dy)*10 + col0 + u];
            #pragma unroll
            for (int j = 0; j < 9; ++j) {
                const float* wp = wb[j] + c*9 + dy*3;
                float w0 = wp[0], w1 = wp[1], w2 = wp[2];
                #pragma unroll
                for (int u = 0; u < 4; ++u)
                    acc[j][u] += w0*xv[u] + w1*xv[u+1] + w2*xv[u+2];
            }
        }
    }
    int tbase = (ty0 + row) * 96 + tx0 + col0;
    #pragma unroll
    for (int j = 0; j < 9; ++j)
        #pragma unroll
        for (int u = 0; u < 4; ++u) {
            float v = acc[j][u] + bias[j];
            op[j][(size_t)(tbase + u) * ostr[j]] = v > 0.f ? v : 0.f;
        }
}

// ---------------- K2: LSH codes + normalized queries xn ----------------
__global__ __launch_bounds__(256) void k_codes(
    const float* __restrict__ xe, const float* __restrict__ rot,
    unsigned char* __restrict__ codes, float* __restrict__ xn)
{
    __shared__ float rotT[4096];   // [h*64+i][16]
    int tid = threadIdx.x;
    for (int e = tid; e < 4096; e += 256) {
        int f = e >> 8, r = e & 255;
        rotT[r * 16 + f] = rot[f * 256 + r];   // rot is (16,4,64)
    }
    __syncthreads();
    int P = blockIdx.x * 64 + (tid & 63);
    int h = tid >> 6;
    int n = P / LL, t = P % LL;
    const float4* xp = (const float4*)(xe + ((size_t)n * LL + t) * 16);
    float4 q0 = xp[0], q1 = xp[1], q2 = xp[2], q3 = xp[3];
    if (h == 0) {
        float nn = dot4(q0,q0) + dot4(q1,q1) + dot4(q2,q2) + dot4(q3,q3);
        float s = fmaxf(sqrtf(nn), EPS_N);
        float inv = 1.f / s;
        float4* dst = (float4*)(xn + ((size_t)n * LL + t) * 16);
        dst[0] = make_float4(q0.x*inv, q0.y*inv, q0.z*inv, q0.w*inv);
        dst[1] = make_float4(q1.x*inv, q1.y*inv, q1.z*inv, q1.w*inv);
        dst[2] = make_float4(q2.x*inv, q2.y*inv, q2.z*inv, q2.w*inv);
        dst[3] = make_float4(q3.x*inv, q3.y*inv, q3.z*inv, q3.w*inv);
    }
    float best = -1e30f; int bi = 0;
    const float* rp = rotT + h * 1024;
    for (int i = 0; i < 64; ++i) {
        const float4* r4 = (const float4*)(rp + i * 16);
        float v = dot4(q0, r4[0]) + dot4(q1, r4[1]) + dot4(q2, r4[2]) + dot4(q3, r4[3]);
        if (v > best) { best = v; bi = i; }   // strict > = first max (jnp.argmax)
    }
    codes[(size_t)n * TOT + h * LL + t] = (unsigned char)(h * 64 + bi);
}

// ---------------- K3: stable counting sort (hist -> scan -> place) --------------
// hist layout: [n][bin(256)][seg(144)]
__global__ __launch_bounds__(256) void k_hist(
    const unsigned char* __restrict__ codes, int* __restrict__ hist)
{
    __shared__ int lh[256];
    int b = blockIdx.x, n = b / NSEG, seg = b % NSEG;
    int tid = threadIdx.x;
    lh[tid] = 0;
    __syncthreads();
    int code = codes[(size_t)n * TOT + seg * 256 + tid];
    atomicAdd(&lh[code], 1);
    __syncthreads();
    hist[((size_t)n * 256 + tid) * NSEG + seg] = lh[tid];
}

__global__ void k_scan(int* __restrict__ hist)
{
    __shared__ int sc[256];
    int n = blockIdx.x, bin = threadIdx.x;
    int* hp = hist + ((size_t)n * 256 + bin) * NSEG;
    int4 buf[36];
    int4* hp4 = (int4*)hp;
    #pragma unroll
    for (int q = 0; q < 36; ++q) buf[q] = hp4[q];
    int running = 0;
    #pragma unroll
    for (int q = 0; q < 36; ++q) {
        int t0 = buf[q].x; buf[q].x = running; running += t0;
        int t1 = buf[q].y; buf[q].y = running; running += t1;
        int t2 = buf[q].z; buf[q].z = running; running += t2;
        int t3 = buf[q].w; buf[q].w = running; running += t3;
    }
    sc[bin] = running;
    __syncthreads();
    // Hillis-Steele inclusive scan over bins
    for (int off = 1; off < 256; off <<= 1) {
        int v = sc[bin];
        int u = (bin >= off) ? sc[bin - off] : 0;
        __syncthreads();
        sc[bin] = v + u;
        __syncthreads();
    }
    int bs = sc[bin] - running;   // exclusive prefix over bins
    #pragma unroll
    for (int q = 0; q < 36; ++q) {
        buf[q].x += bs; buf[q].y += bs; buf[q].z += bs; buf[q].w += bs;
        hp4[q] = buf[q];
    }
}

__global__ __launch_bounds__(256) void k_place(
    const unsigned char* __restrict__ codes, const int* __restrict__ hist,
    int* __restrict__ idx)
{
    __shared__ unsigned char cl[256];
    int b = blockIdx.x, n = b / NSEG, seg = b % NSEG;
    int tid = threadIdx.x;
    int my = codes[(size_t)n * TOT + seg * 256 + tid];
    cl[tid] = (unsigned char)my;
    __syncthreads();
    int rank = 0;
    for (int j = 0; j < tid; ++j) rank += (cl[j] == my);
    int pos = hist[((size_t)n * 256 + my) * NSEG + seg] + rank;
    idx[(size_t)n * TOT + pos] = seg * 256 + tid;
}

// ---------------- K4: fused fc1->relu->fc2 per row, bf16 MFMA --------------------
// re2[R,i] = sum_m relu(fe[R,:]@fc1_w[m,:]+b1[m]) * fc2_w[i,m] + b2[i]
// 144 blocks x 128 rows; 4 waves, wave w owns m-tiles {2w, 2w+1}.
__global__ __launch_bounds__(256) void k_fc(
    const float* __restrict__ fe,
    const float* __restrict__ fc1_w, const float* __restrict__ fc1_b,
    const float* __restrict__ fc2_w, const float* __restrict__ fc2_b,
    float* __restrict__ re2)
{
    __shared__ unsigned short w1b[144 * 72];    // [n][k<64], pad 72
    __shared__ unsigned short w2b[144 * 168];   // [i][m<144, 144..167 = 0], pad 168
    __shared__ unsigned short feb[128 * 72];    // [r][k<64]
    __shared__ unsigned short hb [128 * 168];   // [r][m<144, 144..167 = 0]
    int tid = threadIdx.x;
    size_t R0 = (size_t)blockIdx.x * 128;
    // stage weights (bf16) + fe tile
    for (int e = tid; e < 144 * 64; e += 256) {
        int nn = e >> 6, k = e & 63;
        w1b[nn * 72 + k] = f2bf(fc1_w[e]);
    }
    for (int e = tid; e < 144 * 168; e += 256) {
        int ii = e / 168, m = e - ii * 168;
        w2b[e] = (m < 144) ? f2bf(fc2_w[ii * 144 + m]) : 0;
    }
    for (int e = tid; e < 128 * 64; e += 256) {
        int r = e >> 6, k = e & 63;
        feb[r * 72 + k] = f2bf(fe[(R0 + r) * 64 + k]);
    }
    for (int e = tid; e < 128 * 24; e += 256) {   // zero hid k-pad
        int r = e / 24, m = 144 + e % 24;
        hb[r * 168 + m] = 0;
    }
    __syncthreads();
    int wave = tid >> 6, lane = tid & 63;
    int lcol = lane & 15, quad = lane >> 4;
    // GEMM1: hid = relu(fe @ w1^T + b1)
    #pragma unroll
    for (int mi = 0; mi < 2; ++mi) {
        int mt = wave * 2 + mi;
        int arow = mt * 16 + lcol;
        bf16x8 a0 = *(bf16x8*)(feb + arow * 72 + quad * 8);
        bf16x8 a1 = *(bf16x8*)(feb + arow * 72 + 32 + quad * 8);
        #pragma unroll
        for (int nt = 0; nt < 9; ++nt) {
            int bn = nt * 16 + lcol;
            bf16x8 b0 = *(bf16x8*)(w1b + bn * 72 + quad * 8);
            bf16x8 b1 = *(bf16x8*)(w1b + bn * 72 + 32 + quad * 8);
            f32x4 acc = {0.f, 0.f, 0.f, 0.f};
            acc = __builtin_amdgcn_mfma_f32_16x16x32_bf16(a0, b0, acc, 0, 0, 0);
            acc = __builtin_amdgcn_mfma_f32_16x16x32_bf16(a1, b1, acc, 0, 0, 0);
            int col = nt * 16 + lcol;
            float bb = fc1_b[col];
            #pragma unroll
            for (int r = 0; r < 4; ++r) {
                int row = mt * 16 + quad * 4 + r;
                float v = acc[r] + bb;
                hb[row * 168 + col] = f2bf(v > 0.f ? v : 0.f);
            }
        }
    }
    __syncthreads();
    // GEMM2: re2 = hid @ w2^T + b2 (K=160, zero-padded)
    #pragma unroll
    for (int mi = 0; mi < 2; ++mi) {
        int mt = wave * 2 + mi;
        int arow = mt * 16 + lcol;
        #pragma unroll
        for (int nt = 0; nt < 9; ++nt) {
            int bn = nt * 16 + lcol;
            f32x4 acc = {0.f, 0.f, 0.f, 0.f};
            #pragma unroll
            for (int kk = 0; kk < 5; ++kk) {
                bf16x8 a = *(bf16x8*)(hb  + arow * 168 + kk * 32 + quad * 8);
                bf16x8 b = *(bf16x8*)(w2b + bn  * 168 + kk * 32 + quad * 8);
                acc = __builtin_amdgcn_mfma_f32_16x16x32_bf16(a, b, acc, 0, 0, 0);
            }
            int col = nt * 16 + lcol;
            float bb = fc2_b[col];
            #pragma unroll
            for (int r = 0; r < 4; ++r) {
                int row = mt * 16 + quad * 4 + r;
                re2[(R0 + row) * 144 + col] = acc[r] + bb;
            }
        }
    }
}

// ---------------- K5: bucketed attention (gather + QK^T + softmax + PV) ----------
// one block per (n,h,chunk): 512 blocks, 256 threads
__global__ __launch_bounds__(256) void k_attn(
    const float* __restrict__ xe, const float* __restrict__ xn,
    const float* __restrict__ ye, const float* __restrict__ re2,
    const int* __restrict__ idx,
    float* __restrict__ ret, float* __restrict__ bsc)
{
    __shared__ float xs_s[144 * 16];    // unnormalized query rows
    __shared__ int   t_arr[432];
    __shared__ float m_run[144], l_run[144], alpha_arr[144];
    __shared__ float raw_t[144 * 52];   // stride 52: 20i mod 32 -> 8 bank groups
    __shared__ float xnc[48 * 20];      // normalized key tile, stride 20
    __shared__ float ya_t[48 * 64];     // value tile

    int b = blockIdx.x;
    int n = b >> 8, rem = b & 255;
    int h = rem >> 6, k = rem & 63;
    int tid = threadIdx.x;

    for (int r = tid; r < 432; r += 256) {
        int region = r / 144, i = r - region * 144;
        int dk = (region == 0) ? 0 : (region == 1 ? -1 : 1);
        int ck = (k + dk + 64) & 63;
        t_arr[r] = idx[(size_t)n * TOT + h * LL + ck * CHK + i] - h * LL;
    }
    if (tid < 144) { m_run[tid] = -1e30f; l_run[tid] = 0.f; }
    __syncthreads();
    for (int e4 = tid; e4 < 576; e4 += 256) {
        int r = e4 >> 2, q = e4 & 3;
        *(float4*)(xs_s + r * 16 + q * 4) =
            *(const float4*)(xe + ((size_t)n * LL + t_arr[r]) * 16 + q * 4);
    }
    float4 acc4[9];
    #pragma unroll
    for (int q = 0; q < 9; ++q) acc4[q] = make_float4(0.f, 0.f, 0.f, 0.f);
    int si = tid >> 4, tj = tid & 15;   // qk 16x16 grid
    int cg = tid & 15, ir = tid >> 4;   // pv: c = cg*4.., rows i = ir+16q
    __syncthreads();

    for (int T = 0; T < 9; ++T) {
        int r0 = T * 48;
        // stage fc_raw into raw_t[i*52+j] (coalesced global; LDS 8-way max)
        for (int e = tid; e < 6912; e += 256) {
            int j = e / 144, i = e - j * 144;
            raw_t[i * 52 + j] = re2[((size_t)n * LL + t_arr[r0 + j]) * 144 + i];
        }
        for (int e4 = tid; e4 < 192; e4 += 256) {
            int j = e4 >> 2, q = e4 & 3;
            *(float4*)(xnc + j * 20 + q * 4) =
                *(const float4*)(xn + ((size_t)n * LL + t_arr[r0 + j]) * 16 + q * 4);
        }
        for (int e4 = tid; e4 < 768; e4 += 256) {
            int j = e4 >> 4, c4 = e4 & 15;
            *(float4*)(ya_t + j * 64 + c4 * 4) =
                *(const float4*)(ye + ((size_t)n * LL + t_arr[r0 + j]) * 64 + c4 * 4);
        }
        __syncthreads();
        // qk: raw[i][j] += xs_i . xn_j   (thread: 9 i x 3 j, RMW of own cells)
        {
            float rv[9][3];
            #pragma unroll
            for (int u = 0; u < 9; ++u)
                #pragma unroll
                for (int v = 0; v < 3; ++v)
                    rv[u][v] = raw_t[(si * 9 + u) * 52 + tj * 3 + v];
            float4 xnr[3][4];
            #pragma unroll
            for (int v = 0; v < 3; ++v)
                #pragma unroll
                for (int q = 0; q < 4; ++q)
                    xnr[v][q] = *(const float4*)(xnc + (tj * 3 + v) * 20 + q * 4);
            #pragma unroll
            for (int u = 0; u < 9; ++u) {
                int i = si * 9 + u;
                const float4* xr = (const float4*)(xs_s + i * 16);
                float4 x0 = xr[0], x1 = xr[1], x2 = xr[2], x3 = xr[3];
                #pragma unroll
                for (int v = 0; v < 3; ++v) {
                    float d = dot4(x0, xnr[v][0]) + dot4(x1, xnr[v][1])
                            + dot4(x2, xnr[v][2]) + dot4(x3, xnr[v][3]);
                    raw_t[i * 52 + tj * 3 + v] = rv[u][v] + d;
                }
            }
        }
        __syncthreads();
        // online softmax per row
        if (tid < 144) {
            float4* rp = (float4*)(raw_t + tid * 52);
            float4 rv[12];
            float mt = -1e30f;
            #pragma unroll
            for (int q = 0; q < 12; ++q) {
                rv[q] = rp[q];
                mt = fmaxf(mt, fmaxf(fmaxf(rv[q].x, rv[q].y), fmaxf(rv[q].z, rv[q].w)));
            }
            float mo = m_run[tid];
            float mn = fmaxf(mo, mt);
            float a = __expf(mo - mn);
            float ssum = 0.f;
            #pragma unroll
            for (int q = 0; q < 12; ++q) {
                rv[q].x = __expf(rv[q].x - mn); rv[q].y = __expf(rv[q].y - mn);
                rv[q].z = __expf(rv[q].z - mn); rv[q].w = __expf(rv[q].w - mn);
                ssum += rv[q].x + rv[q].y + rv[q].z + rv[q].w;
                rp[q] = rv[q];
            }
            l_run[tid] = l_run[tid] * a + ssum;
            m_run[tid] = mn;
            alpha_arr[tid] = a;
        }
        __syncthreads();
        // pv: acc = acc*alpha + score @ ya
        {
            #pragma unroll
            for (int q = 0; q < 9; ++q) {
                float a = alpha_arr[ir + 16 * q];
                acc4[q].x *= a; acc4[q].y *= a; acc4[q].z *= a; acc4[q].w *= a;
            }
            for (int jt4 = 0; jt4 < 12; ++jt4) {
                float4 y0 = *(const float4*)(ya_t + (jt4 * 4 + 0) * 64 + cg * 4);
                float4 y1 = *(const float4*)(ya_t + (jt4 * 4 + 1) * 64 + cg * 4);
                float4 y2 = *(const float4*)(ya_t + (jt4 * 4 + 2) * 64 + cg * 4);
                float4 y3 = *(const float4*)(ya_t + (jt4 * 4 + 3) * 64 + cg * 4);
                #pragma unroll
                for (int q = 0; q < 9; ++q) {
                    float4 sv = *(const float4*)(raw_t + (ir + 16 * q) * 52 + jt4 * 4);
                    acc4[q].x += sv.x*y0.x + sv.y*y1.x + sv.z*y2.x + sv.w*y3.x;
                    acc4[q].y += sv.x*y0.y + sv.y*y1.y + sv.z*y2.y + sv.w*y3.y;
                    acc4[q].z += sv.x*y0.z + sv.y*y1.z + sv.z*y2.z + sv.w*y3.z;
                    acc4[q].w += sv.x*y0.w + sv.y*y1.w + sv.z*y2.w + sv.w*y3.w;
                }
            }
        }
        __syncthreads();
    }
    // epilogue: scatter to unsorted (n,h,t) so no undo pass is needed
    if (tid < 144) {
        bsc[((size_t)n * 4 + h) * LL + t_arr[tid]] = m_run[tid] + __logf(l_run[tid]);
    }
    #pragma unroll
    for (int q = 0; q < 9; ++q) {
        int i = ir + 16 * q;
        float inv = 1.f / l_run[i];
        int t = t_arr[i];
        float4 v = acc4[q];
        v.x *= inv; v.y *= inv; v.z *= inv; v.w *= inv;
        *(float4*)(ret + (((size_t)n * 4 + h) * LL + t) * 64 + cg * 4) = v;
    }
}

// ---------------- K6: softmax over rounds + residual, NCHW output ----------------
__global__ __launch_bounds__(256) void k_final(
    const float* __restrict__ ret, const float* __restrict__ bsc,
    const float* __restrict__ x, float* __restrict__ out)
{
    __shared__ float pr[4][64];
    __shared__ float accl[64 * 65];
    int b = blockIdx.x, n = b / 144;
    int t0 = (b % 144) * 64;
    int tid = threadIdx.x;
    if (tid < 64) {
        int t = t0 + tid;
        float b0 = bsc[((size_t)n*4 + 0)*LL + t];
        float b1 = bsc[((size_t)n*4 + 1)*LL + t];
        float b2 = bsc[((size_t)n*4 + 2)*LL + t];
        float b3 = bsc[((size_t)n*4 + 3)*LL + t];
        float mx = fmaxf(fmaxf(b0, b1), fmaxf(b2, b3));
        float e0 = __expf(b0-mx), e1 = __expf(b1-mx), e2 = __expf(b2-mx), e3 = __expf(b3-mx);
        float inv = 1.f / (e0 + e1 + e2 + e3);
        pr[0][tid] = e0*inv; pr[1][tid] = e1*inv; pr[2][tid] = e2*inv; pr[3][tid] = e3*inv;
    }
    __syncthreads();
    int cc = tid & 63, tt4 = tid >> 6;
    #pragma unroll
    for (int q = 0; q < 16; ++q) {
        int tt = tt4 + 4*q;
        int t = t0 + tt;
        float v = 0.f;
        #pragma unroll
        for (int h2 = 0; h2 < 4; ++h2)
            v += ret[(((size_t)n*4 + h2)*LL + t)*64 + cc] * pr[h2][tt];
        accl[cc*65 + tt] = v;
    }
    __syncthreads();
    int tt = tid & 63, c4 = tid >> 6;
    #pragma unroll
    for (int q = 0; q < 16; ++q) {
        int ch = c4 + 4*q;
        size_t o = ((size_t)n*64 + ch)*LL + t0 + tt;
        out[o] = accl[ch*65 + tt] + x[o];   // RES_SCALE = 1.0
    }
}

// ---------------- launcher ----------------
extern "C" void kernel_launch(void* const* d_in, const int* in_sizes, int n_in,
                              void* d_out, int out_size, void* d_ws, size_t ws_size,
                              hipStream_t stream)
{
    const float* x    = (const float*)d_in[0];
    const float* rot  = (const float*)d_in[1];
    const float* wm   = (const float*)d_in[2];
    const float* bm   = (const float*)d_in[3];
    const float* wa   = (const float*)d_in[4];
    const float* ba   = (const float*)d_in[5];
    const float* wf   = (const float*)d_in[6];
    const float* bf   = (const float*)d_in[7];
    const float* fc1w = (const float*)d_in[8];
    const float* fc1b = (const float*)d_in[9];
    const float* fc2w = (const float*)d_in[10];
    const float* fc2b = (const float*)d_in[11];
    float* out = (float*)d_out;

    char* ws = (char*)d_ws;
    float* xe            = (float*)(ws + 0);          // 2*9216*16  f32
    float* ye            = (float*)(ws + 1179648);    // 2*9216*64  f32
    float* fe            = (float*)(ws + 5898240);    // 2*9216*64  f32
    float* xn            = (float*)(ws + 10616832);   // 2*9216*16  f32
    float* re2           = (float*)(ws + 11796480);   // 2*9216*144 f32
    unsigned char* codes = (unsigned char*)(ws + 22413312);  // 2*36864 u8
    int* hist            = (int*)(ws + 22487040);     // 2*256*144 i32
    int* idxb            = (int*)(ws + 22781952);     // 2*36864 i32
    float* retb          = (float*)(ws + 23076864);   // 2*4*9216*64 f32
    float* bscb          = (float*)(ws + 41951232);   // 2*36864 f32 (end: 42,246,144)

    k_conv <<<288, 256, 0, stream>>>(x, wm, bm, wa, ba, wf, bf, xe, ye, fe);
    k_codes<<<288, 256, 0, stream>>>(xe, rot, codes, xn);
    k_hist <<<288, 256, 0, stream>>>(codes, hist);
    k_scan <<<2,   256, 0, stream>>>(hist);
    k_place<<<288, 256, 0, stream>>>(codes, hist, idxb);
    k_fc   <<<144, 256, 0, stream>>>(fe, fc1w, fc1b, fc2w, fc2b, re2);
    k_attn <<<512, 256, 0, stream>>>(xe, xn, ye, re2, idxb, retb, bscb);
    k_final<<<288, 256, 0, stream>>>(retb, bscb, x, out);
}